// Round 1
// baseline (858.599 us; speedup 1.0000x reference)
//
#include <hip/hip_runtime.h>
#include <hip/hip_bf16.h>

// out[b,t,n] = out[b,t-1,n] * sigmoid(w) + X[b,t,n]
// B=16, T=256, N=32768, fp32. Memory-bound streaming scan along t.
// One thread per 4 consecutive n (float4 loads/stores, 16 B/lane).

#ifndef AXON_B
#define AXON_B 16
#endif
#define AXON_T 256
#define AXON_N 32768

__global__ __launch_bounds__(256) void axon_scan_kernel(
    const float4* __restrict__ X, const float* __restrict__ wp,
    float4* __restrict__ out)
{
    constexpr int T  = AXON_T;
    constexpr int N4 = AXON_N / 4;           // 8192 float4 per (b,t) row

    const int idx = blockIdx.x * blockDim.x + threadIdx.x;  // [0, B*N4)
    const int b   = idx / N4;
    const int n4  = idx - b * N4;

    // sigmoid(w); w==0 in the reference setup -> a = 0.5 exactly
    const float a = 1.0f / (1.0f + expf(-wp[0]));

    // base index in float4 units; max index = 16*256*8192 = 2^25, fits int
    int off = (b * T) * N4 + n4;

    float4 c = make_float4(0.0f, 0.0f, 0.0f, 0.0f);

    #pragma unroll 4
    for (int t = 0; t < T; ++t, off += N4) {
        const float4 x = X[off];
        c.x = fmaf(c.x, a, x.x);
        c.y = fmaf(c.y, a, x.y);
        c.z = fmaf(c.z, a, x.z);
        c.w = fmaf(c.w, a, x.w);
        out[off] = c;
    }
}

extern "C" void kernel_launch(void* const* d_in, const int* in_sizes, int n_in,
                              void* d_out, int out_size, void* d_ws, size_t ws_size,
                              hipStream_t stream)
{
    const float4* X  = (const float4*)d_in[0];
    const float*  wp = (const float*)d_in[1];
    float4*       out = (float4*)d_out;

    const int total_threads = AXON_B * (AXON_N / 4);   // 131072
    const int block = 256;
    const int grid  = (total_threads + block - 1) / block;  // 512

    axon_scan_kernel<<<grid, block, 0, stream>>>(X, wp, out);
}